// Round 1
// baseline (137.497 us; speedup 1.0000x reference)
//
#include <hip/hip_runtime.h>
#include <math.h>

// Box-embedding conditional-probability loss.
// R5: force the MLP experiment that R3/R4 failed to materialize (VGPR stayed
// 36 both times -> loads were still sunk into compute by regalloc, so the
// "fabric-bound" conclusion was never actually tested). All 16 row gathers
// are issued as opaque inline-asm global_load_dwordx4 with immediate
// offsets (regalloc cannot sink or split them), then consumed in two halves
// behind s_waitcnt vmcnt(8)/vmcnt(0) whose operands are "+v"-tied to the
// payload (rule #18: register-only FMAs are not ordered by "memory", so the
// tie + sched_barrier(0) is the only sound fence).
// Predict: VGPR ~90-120, occupancy ~50%. Latency-bound -> dur <= 42us.
// Fabric-bound -> dur unchanged ~46us, and that is the roofline.

#define EPSF 1e-8f

typedef float f32x4 __attribute__((ext_vector_type(4)));

// One address register pair per table row; rows are 512B so the 4 chunks sit
// at immediate offsets 0/128/256/384 (13-bit signed imm, fine).
#define GLOAD(dst, ptr, OFF)                                          \
    asm volatile("global_load_dwordx4 %0, %1, off offset:" #OFF      \
                 : "=v"(dst) : "v"(ptr))

__global__ __launch_bounds__(256, 4) void box_loss_kernel(
    const int* __restrict__ t1x, const int* __restrict__ t2x,
    const float* __restrict__ min_t, const float* __restrict__ delta_t,
    float* __restrict__ out, int B)
{
    const float MIN_MEAN   = (float)((0.0001 + 0.01) / 2.0);          // 0.00505
    const float MIN_VAR    = (float)(0.01 - (0.0001 + 0.01) / 2.0);   // 0.00495
    const float DELTA_MEAN = (float)((0.9 + 0.999) / 2.0);            // 0.9495
    const float DELTA_VAR  = (float)(0.999 - (0.9 + 0.999) / 2.0);    // 0.0495

    int gid  = blockIdx.x * blockDim.x + threadIdx.x;
    int s    = gid >> 3;            // one 8-lane group per sample
    int lane = threadIdx.x & 7;
    if (s >= B) return;

    size_t i1 = (size_t)t1x[s];
    size_t i2 = (size_t)t2x[s];

    const float* pm1 = min_t   + i1 * 128 + lane * 4;
    const float* pd1 = delta_t + i1 * 128 + lane * 4;
    const float* pm2 = min_t   + i2 * 128 + lane * 4;
    const float* pd2 = delta_t + i2 * 128 + lane * 4;

    // ---- issue ALL 16 gathers back-to-back (volatile asm order is fixed) ----
    f32x4 a1[4], b1[4], a2[4], b2[4];
    GLOAD(a1[0], pm1, 0);   GLOAD(b1[0], pd1, 0);
    GLOAD(a2[0], pm2, 0);   GLOAD(b2[0], pd2, 0);
    GLOAD(a1[1], pm1, 128); GLOAD(b1[1], pd1, 128);
    GLOAD(a2[1], pm2, 128); GLOAD(b2[1], pd2, 128);
    GLOAD(a1[2], pm1, 256); GLOAD(b1[2], pd1, 256);
    GLOAD(a2[2], pm2, 256); GLOAD(b2[2], pd2, 256);
    GLOAD(a1[3], pm1, 384); GLOAD(b1[3], pd1, 384);
    GLOAD(a2[3], pm2, 384); GLOAD(b2[3], pd2, 384);

    float p1 = 1.f, p2 = 1.f, pm = 1.f, pj = 1.f;
    float wmin = 1e30f;   // running min of meet width -> disjoint iff <= 0

    // ---- first half: wait for the oldest 8 loads, keep 8 in flight ----
    asm volatile("s_waitcnt vmcnt(8)"
        : "+v"(a1[0]), "+v"(b1[0]), "+v"(a2[0]), "+v"(b2[0]),
          "+v"(a1[1]), "+v"(b1[1]), "+v"(a2[1]), "+v"(b2[1]));
#if defined(__has_builtin)
#if __has_builtin(__builtin_amdgcn_sched_barrier)
    __builtin_amdgcn_sched_barrier(0);
#endif
#endif

    #pragma unroll
    for (int c = 0; c < 2; ++c) {
        #pragma unroll
        for (int k = 0; k < 4; ++k) {
            float t1min = fmaf(a1[c][k], MIN_VAR, MIN_MEAN);
            float w1    = fmaf(b1[c][k], DELTA_VAR, DELTA_MEAN);
            float t2min = fmaf(a2[c][k], MIN_VAR, MIN_MEAN);
            float w2    = fmaf(b2[c][k], DELTA_VAR, DELTA_MEAN);
            float t1max = t1min + w1;
            float t2max = t2min + w2;

            float mm_ = fmaxf(t1min, t2min);
            float mM_ = fminf(t1max, t2max);
            float jm_ = fminf(t1min, t2min);
            float jM_ = fmaxf(t1max, t2max);

            float wm = mM_ - mm_;
            float wj = jM_ - jm_;

            wmin = fminf(wmin, wm);
            p1 *= w1;                       // w1,w2 ~ 0.95 +- 0.05*N(0,1): > 0
            p2 *= w2;
            pm *= fmaxf(wm, EPSF);
            pj *= wj;
        }
    }

    // ---- second half ----
    asm volatile("s_waitcnt vmcnt(0)"
        : "+v"(a1[2]), "+v"(b1[2]), "+v"(a2[2]), "+v"(b2[2]),
          "+v"(a1[3]), "+v"(b1[3]), "+v"(a2[3]), "+v"(b2[3]));
#if defined(__has_builtin)
#if __has_builtin(__builtin_amdgcn_sched_barrier)
    __builtin_amdgcn_sched_barrier(0);
#endif
#endif

    #pragma unroll
    for (int c = 2; c < 4; ++c) {
        #pragma unroll
        for (int k = 0; k < 4; ++k) {
            float t1min = fmaf(a1[c][k], MIN_VAR, MIN_MEAN);
            float w1    = fmaf(b1[c][k], DELTA_VAR, DELTA_MEAN);
            float t2min = fmaf(a2[c][k], MIN_VAR, MIN_MEAN);
            float w2    = fmaf(b2[c][k], DELTA_VAR, DELTA_MEAN);
            float t1max = t1min + w1;
            float t2max = t2min + w2;

            float mm_ = fmaxf(t1min, t2min);
            float mM_ = fminf(t1max, t2max);
            float jm_ = fminf(t1min, t2min);
            float jM_ = fmaxf(t1max, t2max);

            float wm = mM_ - mm_;
            float wj = jM_ - jm_;

            wmin = fminf(wmin, wm);
            p1 *= w1;
            p2 *= w2;
            pm *= fmaxf(wm, EPSF);
            pj *= wj;
        }
    }

    // one log per quantity per lane (products of 16 widths: ~[0.2, 2], safe)
    float l1 = __logf(p1);
    float l2 = __logf(p2);
    float lm = __logf(pm);
    float lj = __logf(pj);

    // butterfly across the 8-lane group (masks 4,2,1 stay in-group)
    #pragma unroll
    for (int m = 4; m >= 1; m >>= 1) {
        l1   += __shfl_xor(l1,   m, 64);
        l2   += __shfl_xor(l2,   m, 64);
        lm   += __shfl_xor(lm,   m, 64);
        lj   += __shfl_xor(lj,   m, 64);
        wmin  = fminf(wmin, __shfl_xor(wmin, m, 64));
    }

    if (lane == 0) {
        float cond = lm - l2;
        float pos, neg;
        if (wmin <= 0.f) {                  // disjoint
            pos = lj - l1;                  // -(t1_log - join_log)
            neg = 0.f;
        } else {
            pos = -cond;
            // precise path: cancellation near cond==0
            neg = -logf(fmaxf(1.f - expf(cond), EPSF));
        }
        out[s]     = pos;   // train_pos_prob
        out[B + s] = neg;   // train_neg_prob
    }
}

extern "C" void kernel_launch(void* const* d_in, const int* in_sizes, int n_in,
                              void* d_out, int out_size, void* d_ws, size_t ws_size,
                              hipStream_t stream) {
    const int*   t1x     = (const int*)d_in[0];
    const int*   t2x     = (const int*)d_in[1];
    const float* min_t   = (const float*)d_in[2];
    const float* delta_t = (const float*)d_in[3];
    float*       out     = (float*)d_out;

    int B = in_sizes[0];
    int threads = 256;                       // 32 samples per block
    int blocks  = (B * 8 + threads - 1) / threads;
    box_loss_kernel<<<blocks, threads, 0, stream>>>(t1x, t2x, min_t, delta_t, out, B);
}

// Round 5
// 135.667 us; speedup vs baseline: 1.0135x; 1.0135x over previous
//
#include <hip/hip_runtime.h>
#include <math.h>

// Box-embedding conditional-probability loss.
// R9: same experiment as R7/R8 (both hit "MI355X container failed twice" at
// the broker level -- never reached the chip). Kernel symbol renamed and
// comments touched so every artifact hash differs, in case the failure is a
// poisoned cache keyed on the binary. Experiment is unchanged:
// decisive MLP-vs-fabric test with plain C loads. Each 8-lane group handles
// TWO samples (s, s+B/2); all 32 dwordx4 gathers are issued before either
// compute block, so the compiler's counted vmcnt keeps sample-B's 16 loads
// in flight under sample-A's compute. __launch_bounds__(256,2) raises the
// per-wave VGPR budget (~256) so the ~128-VGPR payload can stay live.
// Freshness tripwire: this structure cannot compile to 36 VGPRs without
// visible scratch traffic -- a third 36-VGPR reading means stale binaries.
// Predict: VGPR ~140-180, occupancy ~25%. Latency-bound -> warm dispatch
// <= 33us. Fabric-bound -> unchanged ~42.7us (268MB / 6.29 TB/s = roofline).

#define EPSF 1e-8f

typedef float f32x4 __attribute__((ext_vector_type(4)));

__device__ __forceinline__ void compute_store(
    const f32x4 (&A1)[4], const f32x4 (&B1)[4],
    const f32x4 (&A2)[4], const f32x4 (&B2)[4],
    float* __restrict__ out, int B, int s, int k)
{
    const float MIN_MEAN   = (float)((0.0001 + 0.01) / 2.0);          // 0.00505
    const float MIN_VAR    = (float)(0.01 - (0.0001 + 0.01) / 2.0);   // 0.00495
    const float DELTA_MEAN = (float)((0.9 + 0.999) / 2.0);            // 0.9495
    const float DELTA_VAR  = (float)(0.999 - (0.9 + 0.999) / 2.0);    // 0.0495

    float p1 = 1.f, p2 = 1.f, pm = 1.f, pj = 1.f;
    float wmin = 1e30f;   // running min of meet width -> disjoint iff <= 0

    #pragma unroll
    for (int c = 0; c < 4; ++c) {
        #pragma unroll
        for (int q = 0; q < 4; ++q) {
            float t1min = fmaf(A1[c][q], MIN_VAR, MIN_MEAN);
            float w1    = fmaf(B1[c][q], DELTA_VAR, DELTA_MEAN);
            float t2min = fmaf(A2[c][q], MIN_VAR, MIN_MEAN);
            float w2    = fmaf(B2[c][q], DELTA_VAR, DELTA_MEAN);
            float t1max = t1min + w1;
            float t2max = t2min + w2;

            float mm_ = fmaxf(t1min, t2min);
            float mM_ = fminf(t1max, t2max);
            float jm_ = fminf(t1min, t2min);
            float jM_ = fmaxf(t1max, t2max);

            float wm = mM_ - mm_;           // meet width (may be <= 0)
            float wj = jM_ - jm_;           // join width (>= w1 > 0)

            wmin = fminf(wmin, wm);
            p1 *= w1;                       // w1,w2 ~ 0.95 +- 0.05*N(0,1): > 0
            p2 *= w2;
            pm *= fmaxf(wm, EPSF);
            pj *= wj;
        }
    }

    // one log per quantity per lane (products of 16 widths: ~[0.2, 2], safe)
    float l1 = __logf(p1);
    float l2 = __logf(p2);
    float lm = __logf(pm);
    float lj = __logf(pj);

    // butterfly across the 8-lane group (masks 4,2,1 stay in-group)
    #pragma unroll
    for (int m = 4; m >= 1; m >>= 1) {
        l1   += __shfl_xor(l1,   m, 64);
        l2   += __shfl_xor(l2,   m, 64);
        lm   += __shfl_xor(lm,   m, 64);
        lj   += __shfl_xor(lj,   m, 64);
        wmin  = fminf(wmin, __shfl_xor(wmin, m, 64));
    }

    if (k == 0) {
        float cond = lm - l2;
        float pos, neg;
        if (wmin <= 0.f) {                  // disjoint
            pos = lj - l1;                  // -(t1_log - join_log)
            neg = 0.f;
        } else {
            pos = -cond;
            // precise path: cancellation near cond==0
            neg = -logf(fmaxf(1.f - expf(cond), EPSF));
        }
        out[s]     = pos;   // train_pos_prob
        out[B + s] = neg;   // train_neg_prob
    }
}

__global__ __launch_bounds__(256, 2) void box_loss_pipe2_kernel(
    const int* __restrict__ t1x, const int* __restrict__ t2x,
    const float* __restrict__ min_t, const float* __restrict__ delta_t,
    float* __restrict__ out, int B)
{
    const int gid  = blockIdx.x * blockDim.x + threadIdx.x;
    const int grp  = gid >> 3;          // 8-lane group id: 0 .. half-1
    const int k    = gid & 7;           // lane in group
    const int half = (B + 1) >> 1;

    const int sA = grp;                 // first sample
    const int sB = grp + half;          // second sample (may not exist)
    if (sA >= B) return;
    const bool hasB = (sB < B);

    // ---- indices for both samples up front ----
    const size_t i1a = (size_t)t1x[sA];
    const size_t i2a = (size_t)t2x[sA];
    const int    sBc = hasB ? sB : sA;  // clamp: duplicate work, masked store
    const size_t i1b = (size_t)t1x[sBc];
    const size_t i2b = (size_t)t2x[sBc];

    const f32x4* m1a = reinterpret_cast<const f32x4*>(min_t   + i1a * 128);
    const f32x4* d1a = reinterpret_cast<const f32x4*>(delta_t + i1a * 128);
    const f32x4* m2a = reinterpret_cast<const f32x4*>(min_t   + i2a * 128);
    const f32x4* d2a = reinterpret_cast<const f32x4*>(delta_t + i2a * 128);
    const f32x4* m1b = reinterpret_cast<const f32x4*>(min_t   + i1b * 128);
    const f32x4* d1b = reinterpret_cast<const f32x4*>(delta_t + i1b * 128);
    const f32x4* m2b = reinterpret_cast<const f32x4*>(min_t   + i2b * 128);
    const f32x4* d2b = reinterpret_cast<const f32x4*>(delta_t + i2b * 128);

    // ---- issue ALL 32 gathers (16 per sample) before any compute ----
    f32x4 a1[4], b1[4], a2[4], b2[4];   // sample A payload (64 VGPRs)
    f32x4 c1[4], e1[4], c2[4], e2[4];   // sample B payload (64 VGPRs)
    #pragma unroll
    for (int c = 0; c < 4; ++c) {
        const int off = c * 8 + k;
        a1[c] = m1a[off];
        b1[c] = d1a[off];
        a2[c] = m2a[off];
        b2[c] = d2a[off];
    }
    #pragma unroll
    for (int c = 0; c < 4; ++c) {
        const int off = c * 8 + k;
        c1[c] = m1b[off];
        e1[c] = d1b[off];
        c2[c] = m2b[off];
        e2[c] = d2b[off];
    }

    // compute sample A first: compiler waits only on A's loads (counted
    // vmcnt), leaving B's 16 loads in flight under A's VALU work.
    compute_store(a1, b1, a2, b2, out, B, sA, k);
    if (hasB)
        compute_store(c1, e1, c2, e2, out, B, sB, k);
}

extern "C" void kernel_launch(void* const* d_in, const int* in_sizes, int n_in,
                              void* d_out, int out_size, void* d_ws, size_t ws_size,
                              hipStream_t stream) {
    const int*   t1x     = (const int*)d_in[0];
    const int*   t2x     = (const int*)d_in[1];
    const float* min_t   = (const float*)d_in[2];
    const float* delta_t = (const float*)d_in[3];
    float*       out     = (float*)d_out;

    int B = in_sizes[0];
    int half    = (B + 1) >> 1;            // groups needed (2 samples/group)
    int threads = 256;                     // 32 groups per block
    int blocks  = (half * 8 + threads - 1) / threads;
    box_loss_pipe2_kernel<<<blocks, threads, 0, stream>>>(t1x, t2x, min_t, delta_t, out, B);
}